// Round 5
// baseline (295.798 us; speedup 1.0000x reference)
//
#include <hip/hip_runtime.h>
#include <cstdint>

// SNN (2-layer LIF, 10 timesteps) — one thread per batch element.
// Bit-exact JAX emulation (verified absmax=0 in R1..R4):
//  - threefry2x32-20, key=(0,42), partitionable counter mode, out = x0^x1
//  - spike compare in integer domain: u < x  <=>  (h>>9) < ceil(x*2^23)
//  - rotates = v_alignbit_b32 via builtin (R2 formulation — measured best)
//  - LIF elementwise ops with explicit single-rounded intrinsics
//  - dots as ascending fma chains from 0, then (i_dec + dot_in) + dot_rec
//  - manual DCE: sp(t=8), sp(t=9) + step-8/9 dead state elided (96 hashes)
//
// R5 CHANGE: t-loop ROLLED (#pragma unroll 1). Fully-unrolled body was
// ~53 KB straight-line code (> 32 KB L1I) — every wave streamed its entire
// instruction footprint from L2 with zero reuse. Rolled body ~6.6 KB fits
// L1I after the first iteration. Manual step-8/9 DCE is now load-bearing
// (compiler can't DCE across rolled iterations).

#define TFR(r) { x0 += x1; x1 = __builtin_amdgcn_alignbit(x1, x1, 32 - (r)); x1 ^= x0; }

__device__ __forceinline__ uint32_t tf_hash(uint32_t c) {
  // key (0,42): ks0=0, ks1=42, ks2=0x1BD11BDA^42=0x1BD11BF0
  uint32_t x0 = 0u;
  uint32_t x1 = c + 42u;                   // c + ks1
  TFR(13) TFR(15) TFR(26) TFR(6)
  x0 += 42u;          x1 += 0x1BD11BF1u;   // ks1, ks2+1
  TFR(17) TFR(29) TFR(16) TFR(24)
  x0 += 0x1BD11BF0u;  x1 += 2u;            // ks2, ks0+2
  TFR(13) TFR(15) TFR(26) TFR(6)
  /* x0 += 0 */       x1 += 45u;           // ks0, ks1+3
  TFR(17) TFR(29) TFR(16) TFR(24)
  x0 += 42u;          x1 += 0x1BD11BF4u;   // ks1, ks2+4
  TFR(13) TFR(15) TFR(26) TFR(6)
  x0 += 0x1BD11BF0u;  x1 += 5u;            // ks2, ks0+5
  return x0 ^ x1;
}

__global__ __launch_bounds__(256) void snn_kernel(
    const float* __restrict__ x_in, const float* __restrict__ w_in0,
    const float* __restrict__ w_rec0, const float* __restrict__ w_in1,
    const float* __restrict__ w_rec1, float* __restrict__ out, int B)
{
  int b = blockIdx.x * blockDim.x + threadIdx.x;
  if (b >= B) return;

  // ---- integer spike thresholds: T[j] = ceil(x[j] * 2^23), exact ----
  uint32_t T[12];
  {
    const float4* xv = reinterpret_cast<const float4*>(x_in + (size_t)b * 12);
    float4 q0 = xv[0], q1 = xv[1], q2 = xv[2];
    float x[12] = {q0.x,q0.y,q0.z,q0.w, q1.x,q1.y,q1.z,q1.w, q2.x,q2.y,q2.z,q2.w};
    #pragma unroll
    for (int j = 0; j < 12; ++j)
      T[j] = (uint32_t)__builtin_ceilf(x[j] * 8388608.0f);
  }

  // ---- weights (wave-uniform -> SGPRs via s_load) ----
  float W0[6][12], R0[6][6], W1[6], R1;
  #pragma unroll
  for (int n = 0; n < 6; ++n) {
    #pragma unroll
    for (int j = 0; j < 12; ++j) W0[n][j] = w_in0[n * 12 + j];
  }
  #pragma unroll
  for (int n = 0; n < 6; ++n) {
    #pragma unroll
    for (int j = 0; j < 6; ++j) R0[n][j] = w_rec0[n * 6 + j];
  }
  #pragma unroll
  for (int j = 0; j < 6; ++j) W1[j] = w_in1[j];
  R1 = w_rec1[0];

  // ---- state ----
  float v0[6], i0[6], z0[6];
  #pragma unroll
  for (int n = 0; n < 6; ++n) { v0[n] = 0.0f; i0[n] = 0.0f; z0[n] = 0.0f; }
  float v1 = 0.0f, i1 = 0.0f, z1 = 0.0f;

  const uint32_t t_stride = (uint32_t)B * 12u;
  uint32_t base = (uint32_t)b * 12u;   // counter for (t, b, 0); += t_stride per step

  // ---- steps 0..7: full computation, ROLLED loop (fits L1I) ----
  #pragma unroll 1
  for (int t = 0; t < 8; ++t) {
    // Poisson spikes (integer-domain compare, bit-exact)
    float sp[12];
    #pragma unroll
    for (int j = 0; j < 12; ++j) {
      uint32_t h = tf_hash(base + (uint32_t)j);
      sp[j] = ((h >> 9) < T[j]) ? 1.0f : 0.0f;
    }
    base += t_stride;

    // layer 0: 6 LIF neurons
    float zn[6], vn[6], inew[6];
    #pragma unroll
    for (int n = 0; n < 6; ++n) {
      float vdec = __fadd_rn(v0[n], __fmul_rn(0.1f, __fsub_rn(i0[n], v0[n])));
      float idec = __fsub_rn(i0[n], __fmul_rn(0.2f, i0[n]));
      bool fire = (vdec > 1.0f);          // == (vdec - 1.0f) > 0, exactly
      zn[n] = fire ? 1.0f : 0.0f;
      vn[n] = fire ? 0.0f : vdec;
      float d1 = 0.0f;
      #pragma unroll
      for (int j = 0; j < 12; ++j) d1 = __fmaf_rn(sp[j], W0[n][j], d1);
      float d2 = 0.0f;
      #pragma unroll
      for (int j = 0; j < 6; ++j) d2 = __fmaf_rn(z0[j], R0[n][j], d2);
      inew[n] = __fadd_rn(__fadd_rn(idec, d1), d2);
    }

    // layer 1: 1 LIF neuron (input = NEW z0, recurrence = OLD z1)
    {
      float vdec = __fadd_rn(v1, __fmul_rn(0.1f, __fsub_rn(i1, v1)));
      float idec = __fsub_rn(i1, __fmul_rn(0.2f, i1));
      bool fire = (vdec > 1.0f);
      float z1n = fire ? 1.0f : 0.0f;
      float v1n = fire ? 0.0f : vdec;
      float d1 = 0.0f;
      #pragma unroll
      for (int j = 0; j < 6; ++j) d1 = __fmaf_rn(zn[j], W1[j], d1);
      float d2 = __fmaf_rn(z1, R1, 0.0f);  // K=1 dot
      float i1n = __fadd_rn(__fadd_rn(idec, d1), d2);
      z1 = z1n; v1 = v1n; i1 = i1n;
    }

    // commit layer-0 state
    #pragma unroll
    for (int n = 0; n < 6; ++n) { z0[n] = zn[n]; v0[n] = vn[n]; i0[n] = inew[n]; }
  }

  // ---- step 8 (reduced): layer-0 spike decision only; layer-1 v/i update ----
  float i1_9, v1_9;
  {
    float zn8[6];
    #pragma unroll
    for (int n = 0; n < 6; ++n) {
      float vdec = __fadd_rn(v0[n], __fmul_rn(0.1f, __fsub_rn(i0[n], v0[n])));
      zn8[n] = (vdec > 1.0f) ? 1.0f : 0.0f;
      // i0n(8), v0n(8) feed only discarded state -> skipped (sp(8) dead)
    }
    float vdec = __fadd_rn(v1, __fmul_rn(0.1f, __fsub_rn(i1, v1)));
    float idec = __fsub_rn(i1, __fmul_rn(0.2f, i1));
    bool fire = (vdec > 1.0f);
    v1_9 = fire ? 0.0f : vdec;
    float d1 = 0.0f;
    #pragma unroll
    for (int j = 0; j < 6; ++j) d1 = __fmaf_rn(zn8[j], W1[j], d1);
    float d2 = __fmaf_rn(z1, R1, 0.0f);
    i1_9 = __fadd_rn(__fadd_rn(idec, d1), d2);
  }

  // ---- step 9 (reduced): output spike only ----
  float vdec9 = __fadd_rn(v1_9, __fmul_rn(0.1f, __fsub_rn(i1_9, v1_9)));
  out[b] = (vdec9 > 1.0f) ? 1.0f : 0.0f;
}

extern "C" void kernel_launch(void* const* d_in, const int* in_sizes, int n_in,
                              void* d_out, int out_size, void* d_ws, size_t ws_size,
                              hipStream_t stream) {
  const float* x      = (const float*)d_in[0];   // [B,12]
  const float* w_in0  = (const float*)d_in[1];   // [6,12]
  const float* w_rec0 = (const float*)d_in[2];   // [6,6]
  const float* w_in1  = (const float*)d_in[3];   // [1,6]
  const float* w_rec1 = (const float*)d_in[4];   // [1,1]
  float* out = (float*)d_out;                    // [B,1]

  const int B = out_size;                        // 1048576
  const int block = 256;
  const int grid = (B + block - 1) / block;
  snn_kernel<<<grid, block, 0, stream>>>(x, w_in0, w_rec0, w_in1, w_rec1, out, B);
}

// Round 6
// 292.921 us; speedup vs baseline: 1.0098x; 1.0098x over previous
//
#include <hip/hip_runtime.h>
#include <cstdint>

// SNN (2-layer LIF, 10 timesteps) — one thread per batch element.
// Bit-exact JAX emulation (verified absmax=0 in R1..R5):
//  - threefry2x32-20, key=(0,42), partitionable counter mode, out = x0^x1
//    (hash byte-identical to R2 formulation — measured best; R3's QRI
//     reassociation regressed, do not repeat)
//  - spike compare with PRE-SHIFTED thresholds: (h>>9) < T  <=>  h < (T<<9)
//    exact for T < 2^23 (h = 512q+r, r<512); T = 2^23 saturates to 0xFFFFFFFF
//  - LIF fp32 arithmetic PACKED 2 neurons/instruction via float2 ->
//    v_pk_{fma,add,mul}_f32 (IEEE RN per half => bit-exact, contraction off)
//  - dots as ascending fma chains from 0, then (i_dec + dot_in) + dot_rec
//  - manual DCE: sp(t=8), sp(t=9) + dead step-8/9 state elided (96 hashes)
//  - t-loop fully unrolled (R5 showed rolled loop regresses)

typedef float f32x2 __attribute__((ext_vector_type(2)));

#define TFR(r) { x0 += x1; x1 = __builtin_amdgcn_alignbit(x1, x1, 32 - (r)); x1 ^= x0; }

__device__ __forceinline__ uint32_t tf_hash(uint32_t c) {
  // key (0,42): ks0=0, ks1=42, ks2=0x1BD11BDA^42=0x1BD11BF0
  uint32_t x0 = 0u;
  uint32_t x1 = c + 42u;                   // c + ks1
  TFR(13) TFR(15) TFR(26) TFR(6)
  x0 += 42u;          x1 += 0x1BD11BF1u;   // ks1, ks2+1
  TFR(17) TFR(29) TFR(16) TFR(24)
  x0 += 0x1BD11BF0u;  x1 += 2u;            // ks2, ks0+2
  TFR(13) TFR(15) TFR(26) TFR(6)
  /* x0 += 0 */       x1 += 45u;           // ks0, ks1+3
  TFR(17) TFR(29) TFR(16) TFR(24)
  x0 += 42u;          x1 += 0x1BD11BF4u;   // ks1, ks2+4
  TFR(13) TFR(15) TFR(26) TFR(6)
  x0 += 0x1BD11BF0u;  x1 += 5u;            // ks2, ks0+5
  return x0 ^ x1;
}

__global__ __launch_bounds__(256) void snn_kernel(
    const float* __restrict__ x_in, const float* __restrict__ w_in0,
    const float* __restrict__ w_rec0, const float* __restrict__ w_in1,
    const float* __restrict__ w_rec1, float* __restrict__ out, int B)
{
  int b = blockIdx.x * blockDim.x + threadIdx.x;
  if (b >= B) return;

  // ---- pre-shifted integer spike thresholds ----
  uint32_t Ts[12];
  {
    const float4* xv = reinterpret_cast<const float4*>(x_in + (size_t)b * 12);
    float4 q0 = xv[0], q1 = xv[1], q2 = xv[2];
    float x[12] = {q0.x,q0.y,q0.z,q0.w, q1.x,q1.y,q1.z,q1.w, q2.x,q2.y,q2.z,q2.w};
    #pragma unroll
    for (int j = 0; j < 12; ++j) {
      uint32_t T = (uint32_t)__builtin_ceilf(x[j] * 8388608.0f);
      Ts[j] = (T >= 0x800000u) ? 0xFFFFFFFFu : (T << 9);
    }
  }

  // ---- weights, layer-0 packed as neuron pairs {2p, 2p+1} ----
  f32x2 W0p[3][12], R0p[3][6];
  float W1[6], R1;
  #pragma unroll
  for (int p = 0; p < 3; ++p) {
    #pragma unroll
    for (int j = 0; j < 12; ++j) {
      W0p[p][j].x = w_in0[(2*p)   * 12 + j];
      W0p[p][j].y = w_in0[(2*p+1) * 12 + j];
    }
    #pragma unroll
    for (int j = 0; j < 6; ++j) {
      R0p[p][j].x = w_rec0[(2*p)   * 6 + j];
      R0p[p][j].y = w_rec0[(2*p+1) * 6 + j];
    }
  }
  #pragma unroll
  for (int j = 0; j < 6; ++j) W1[j] = w_in1[j];
  R1 = w_rec1[0];

  // ---- state (layer 0 packed in neuron pairs) ----
  f32x2 v0p[3], i0p[3];
  float z0[6];
  #pragma unroll
  for (int p = 0; p < 3; ++p) { v0p[p] = (f32x2){0.0f, 0.0f}; i0p[p] = (f32x2){0.0f, 0.0f}; }
  #pragma unroll
  for (int n = 0; n < 6; ++n) z0[n] = 0.0f;
  float v1 = 0.0f, i1 = 0.0f, z1 = 0.0f;

  const uint32_t t_stride = (uint32_t)B * 12u;
  uint32_t base = (uint32_t)b * 12u;

  // ---- steps 0..7: full computation, fully unrolled ----
  #pragma unroll
  for (int t = 0; t < 8; ++t) {
    // Poisson spikes (integer compare vs pre-shifted thresholds)
    float sp[12];
    #pragma unroll
    for (int j = 0; j < 12; ++j) {
      uint32_t h = tf_hash(base + (uint32_t)j);
      sp[j] = (h < Ts[j]) ? 1.0f : 0.0f;
    }
    base += t_stride;

    // layer 0: 6 LIF neurons, processed as 3 packed pairs
    float zn[6];
    f32x2 vnp[3], inewp[3];
    #pragma unroll
    for (int p = 0; p < 3; ++p) {
      f32x2 v = v0p[p], i = i0p[p];
      f32x2 vdec, idec;
      {
        #pragma clang fp contract(off)
        f32x2 diff = i - v;            // fsub (x2, packed)
        vdec = v + 0.1f * diff;        // fmul, fadd — 3 roundings, as scalar ref
        idec = i - 0.2f * i;           // fmul, fsub
      }
      bool f0 = vdec.x > 1.0f;         // == (vdec-1 > 0), exactly
      bool f1 = vdec.y > 1.0f;
      zn[2*p]   = f0 ? 1.0f : 0.0f;
      zn[2*p+1] = f1 ? 1.0f : 0.0f;
      f32x2 vn;
      vn.x = f0 ? 0.0f : vdec.x;
      vn.y = f1 ? 0.0f : vdec.y;
      f32x2 d1 = {0.0f, 0.0f};
      #pragma unroll
      for (int j = 0; j < 12; ++j) {
        f32x2 s = {sp[j], sp[j]};
        d1 = __builtin_elementwise_fma(s, W0p[p][j], d1);   // v_pk_fma_f32
      }
      f32x2 d2 = {0.0f, 0.0f};
      #pragma unroll
      for (int j = 0; j < 6; ++j) {
        f32x2 s = {z0[j], z0[j]};
        d2 = __builtin_elementwise_fma(s, R0p[p][j], d2);
      }
      {
        #pragma clang fp contract(off)
        inewp[p] = (idec + d1) + d2;   // two packed fadds, same order as scalar
      }
      vnp[p] = vn;
    }

    // layer 1: 1 LIF neuron (input = NEW z0, recurrence = OLD z1), scalar
    {
      float vdec = __fadd_rn(v1, __fmul_rn(0.1f, __fsub_rn(i1, v1)));
      float idec = __fsub_rn(i1, __fmul_rn(0.2f, i1));
      bool fire = (vdec > 1.0f);
      float z1n = fire ? 1.0f : 0.0f;
      float v1n = fire ? 0.0f : vdec;
      float d1 = 0.0f;
      #pragma unroll
      for (int j = 0; j < 6; ++j) d1 = __fmaf_rn(zn[j], W1[j], d1);
      float d2 = __fmaf_rn(z1, R1, 0.0f);  // K=1 dot
      float i1n = __fadd_rn(__fadd_rn(idec, d1), d2);
      z1 = z1n; v1 = v1n; i1 = i1n;
    }

    // commit layer-0 state
    #pragma unroll
    for (int p = 0; p < 3; ++p) { v0p[p] = vnp[p]; i0p[p] = inewp[p]; }
    #pragma unroll
    for (int n = 0; n < 6; ++n) z0[n] = zn[n];
  }

  // ---- step 8 (reduced): layer-0 spike decision only; layer-1 v/i update ----
  float i1_9, v1_9;
  {
    float zn8[6];
    #pragma unroll
    for (int p = 0; p < 3; ++p) {
      f32x2 v = v0p[p], i = i0p[p];
      f32x2 vdec;
      {
        #pragma clang fp contract(off)
        f32x2 diff = i - v;
        vdec = v + 0.1f * diff;
      }
      zn8[2*p]   = (vdec.x > 1.0f) ? 1.0f : 0.0f;
      zn8[2*p+1] = (vdec.y > 1.0f) ? 1.0f : 0.0f;
      // i0n(8), v0n(8) feed only discarded state -> skipped (sp(8) dead)
    }
    float vdec = __fadd_rn(v1, __fmul_rn(0.1f, __fsub_rn(i1, v1)));
    float idec = __fsub_rn(i1, __fmul_rn(0.2f, i1));
    bool fire = (vdec > 1.0f);
    v1_9 = fire ? 0.0f : vdec;
    float d1 = 0.0f;
    #pragma unroll
    for (int j = 0; j < 6; ++j) d1 = __fmaf_rn(zn8[j], W1[j], d1);
    float d2 = __fmaf_rn(z1, R1, 0.0f);
    i1_9 = __fadd_rn(__fadd_rn(idec, d1), d2);
  }

  // ---- step 9 (reduced): output spike only ----
  float vdec9 = __fadd_rn(v1_9, __fmul_rn(0.1f, __fsub_rn(i1_9, v1_9)));
  out[b] = (vdec9 > 1.0f) ? 1.0f : 0.0f;
}

extern "C" void kernel_launch(void* const* d_in, const int* in_sizes, int n_in,
                              void* d_out, int out_size, void* d_ws, size_t ws_size,
                              hipStream_t stream) {
  const float* x      = (const float*)d_in[0];   // [B,12]
  const float* w_in0  = (const float*)d_in[1];   // [6,12]
  const float* w_rec0 = (const float*)d_in[2];   // [6,6]
  const float* w_in1  = (const float*)d_in[3];   // [1,6]
  const float* w_rec1 = (const float*)d_in[4];   // [1,1]
  float* out = (float*)d_out;                    // [B,1]

  const int B = out_size;                        // 1048576
  const int block = 256;
  const int grid = (B + block - 1) / block;
  snn_kernel<<<grid, block, 0, stream>>>(x, w_in0, w_rec0, w_in1, w_rec1, out, B);
}

// Round 7
// 283.243 us; speedup vs baseline: 1.0443x; 1.0342x over previous
//
#include <hip/hip_runtime.h>
#include <cstdint>

// SNN (2-layer LIF, 10 timesteps) — one thread per batch element.
// FINAL (revert to R2 — measured best at 229.7 µs kernel time).
// Bit-exact JAX emulation (absmax=0 in R1..R6):
//  - threefry2x32-20, key=(0,42), partitionable counter mode, out = x0^x1
//  - spike compare in integer domain: u < x  <=>  (h>>9) < ceil(x*2^23)
//  - rotates forced to v_alignbit_b32 (1 VALU op) via builtin
//  - LIF elementwise ops with explicit single-rounded intrinsics
//  - dots as ascending fma chains from 0, then (i_dec + dot_in) + dot_rec
//  - t-loop fully unrolled; compiler DCEs dead t=8,9 spike hashes (96 live)
//
// Measured dead ends (do not revisit): QRI add3-fusion + pre-shifted
// thresholds (R3, −2.3%), rolled t-loop (R5, −5%: I-fetch footprint is NOT
// the bottleneck; occupancy 32→58% changed nothing), packed v_pk_f32 pairs
// (R6, −4.4%: splat movs ate the fma savings). Bottleneck is the VALU issue
// port at ~99% busy on ~8.6k instr/thread, ~79% of which is 96 irreducible
// serial threefry-20 hashes.

#define TFR(r) { x0 += x1; x1 = __builtin_amdgcn_alignbit(x1, x1, 32 - (r)); x1 ^= x0; }

__device__ __forceinline__ uint32_t tf_hash(uint32_t c) {
  // key (0,42): ks0=0, ks1=42, ks2=0x1BD11BDA^42=0x1BD11BF0
  uint32_t x0 = 0u;
  uint32_t x1 = c + 42u;                   // c + ks1
  TFR(13) TFR(15) TFR(26) TFR(6)
  x0 += 42u;          x1 += 0x1BD11BF1u;   // ks1, ks2+1
  TFR(17) TFR(29) TFR(16) TFR(24)
  x0 += 0x1BD11BF0u;  x1 += 2u;            // ks2, ks0+2
  TFR(13) TFR(15) TFR(26) TFR(6)
  /* x0 += 0 */       x1 += 45u;           // ks0, ks1+3
  TFR(17) TFR(29) TFR(16) TFR(24)
  x0 += 42u;          x1 += 0x1BD11BF4u;   // ks1, ks2+4
  TFR(13) TFR(15) TFR(26) TFR(6)
  x0 += 0x1BD11BF0u;  x1 += 5u;            // ks2, ks0+5
  return x0 ^ x1;
}

__global__ __launch_bounds__(256) void snn_kernel(
    const float* __restrict__ x_in, const float* __restrict__ w_in0,
    const float* __restrict__ w_rec0, const float* __restrict__ w_in1,
    const float* __restrict__ w_rec1, float* __restrict__ out, int B)
{
  int b = blockIdx.x * blockDim.x + threadIdx.x;
  if (b >= B) return;

  // ---- integer spike thresholds: T[j] = ceil(x[j] * 2^23), exact ----
  uint32_t T[12];
  {
    const float4* xv = reinterpret_cast<const float4*>(x_in + (size_t)b * 12);
    float4 q0 = xv[0], q1 = xv[1], q2 = xv[2];
    float x[12] = {q0.x,q0.y,q0.z,q0.w, q1.x,q1.y,q1.z,q1.w, q2.x,q2.y,q2.z,q2.w};
    #pragma unroll
    for (int j = 0; j < 12; ++j)
      T[j] = (uint32_t)__builtin_ceilf(x[j] * 8388608.0f);
  }

  // ---- weights (wave-uniform -> scalar loads) ----
  float W0[6][12], R0[6][6], W1[6], R1;
  #pragma unroll
  for (int n = 0; n < 6; ++n) {
    #pragma unroll
    for (int j = 0; j < 12; ++j) W0[n][j] = w_in0[n * 12 + j];
  }
  #pragma unroll
  for (int n = 0; n < 6; ++n) {
    #pragma unroll
    for (int j = 0; j < 6; ++j) R0[n][j] = w_rec0[n * 6 + j];
  }
  #pragma unroll
  for (int j = 0; j < 6; ++j) W1[j] = w_in1[j];
  R1 = w_rec1[0];

  // ---- state ----
  float v0[6], i0[6], z0[6];
  #pragma unroll
  for (int n = 0; n < 6; ++n) { v0[n] = 0.0f; i0[n] = 0.0f; z0[n] = 0.0f; }
  float v1 = 0.0f, i1 = 0.0f, z1 = 0.0f;

  const uint32_t t_stride = (uint32_t)B * 12u;
  uint32_t base = (uint32_t)b * 12u;   // counter for (t, b, 0); += t_stride per step

  #pragma unroll
  for (int t = 0; t < 10; ++t) {
    // ---- Poisson spikes (integer-domain compare, bit-exact) ----
    float sp[12];
    #pragma unroll
    for (int j = 0; j < 12; ++j) {
      uint32_t h = tf_hash(base + (uint32_t)j);
      sp[j] = ((h >> 9) < T[j]) ? 1.0f : 0.0f;
    }
    base += t_stride;

    // ---- layer 0: 6 LIF neurons ----
    float zn[6], vn[6], inew[6];
    #pragma unroll
    for (int n = 0; n < 6; ++n) {
      float vdec = __fadd_rn(v0[n], __fmul_rn(0.1f, __fsub_rn(i0[n], v0[n])));
      float idec = __fsub_rn(i0[n], __fmul_rn(0.2f, i0[n]));
      bool fire = (vdec > 1.0f);          // == (vdec - 1.0f) > 0, exactly
      zn[n] = fire ? 1.0f : 0.0f;
      vn[n] = fire ? 0.0f : vdec;
      float d1 = 0.0f;
      #pragma unroll
      for (int j = 0; j < 12; ++j) d1 = __fmaf_rn(sp[j], W0[n][j], d1);
      float d2 = 0.0f;
      #pragma unroll
      for (int j = 0; j < 6; ++j) d2 = __fmaf_rn(z0[j], R0[n][j], d2);
      inew[n] = __fadd_rn(__fadd_rn(idec, d1), d2);
    }

    // ---- layer 1: 1 LIF neuron (input = NEW z0, recurrence = OLD z1) ----
    {
      float vdec = __fadd_rn(v1, __fmul_rn(0.1f, __fsub_rn(i1, v1)));
      float idec = __fsub_rn(i1, __fmul_rn(0.2f, i1));
      bool fire = (vdec > 1.0f);
      float z1n = fire ? 1.0f : 0.0f;
      float v1n = fire ? 0.0f : vdec;
      float d1 = 0.0f;
      #pragma unroll
      for (int j = 0; j < 6; ++j) d1 = __fmaf_rn(zn[j], W1[j], d1);
      float d2 = __fmaf_rn(z1, R1, 0.0f);  // K=1 dot
      float i1n = __fadd_rn(__fadd_rn(idec, d1), d2);
      z1 = z1n; v1 = v1n; i1 = i1n;
    }

    // ---- commit layer-0 state ----
    #pragma unroll
    for (int n = 0; n < 6; ++n) { z0[n] = zn[n]; v0[n] = vn[n]; i0[n] = inew[n]; }
  }

  out[b] = z1;  // final-timestep output spike
}

extern "C" void kernel_launch(void* const* d_in, const int* in_sizes, int n_in,
                              void* d_out, int out_size, void* d_ws, size_t ws_size,
                              hipStream_t stream) {
  const float* x      = (const float*)d_in[0];   // [B,12]
  const float* w_in0  = (const float*)d_in[1];   // [6,12]
  const float* w_rec0 = (const float*)d_in[2];   // [6,6]
  const float* w_in1  = (const float*)d_in[3];   // [1,6]
  const float* w_rec1 = (const float*)d_in[4];   // [1,1]
  float* out = (float*)d_out;                    // [B,1]

  const int B = out_size;                        // 1048576
  const int block = 256;
  const int grid = (B + block - 1) / block;
  snn_kernel<<<grid, block, 0, stream>>>(x, w_in0, w_rec0, w_in1, w_rec1, out, B);
}